// Round 5
// baseline (37.683 us; speedup 1.0000x reference)
//
#include <hip/hip_runtime.h>

#define N_VOCAB 50400
#define D_MODEL 4096
#define SHARDS  8
#define SEQ     2048
#define BATCH   2
#define PER_IN  6300   // N_VOCAB / SHARDS

typedef float f4 __attribute__((ext_vector_type(4)));

// Kernel 1: bsum[s][d] = sum_{s'<s} kern[s'*PER_IN+PER_IN-1][d]
//                      + sum_{s'>s} kern[s'*PER_IN][d] + SHARDS*bias[d]
// grid = SHARDS * (D_MODEL/4/256) = 32 blocks.
__global__ __launch_bounds__(256)
void boundary_sums_kernel(const float* __restrict__ kern,
                          const float* __restrict__ bias,
                          float* __restrict__ bsum) {
    const int s  = blockIdx.x >> 2;                  // 0..7
    const int c  = blockIdx.x & 3;                   // 0..3
    const int d4 = c * 256 + threadIdx.x;            // f4 column index, 0..1023

    const f4* __restrict__ kf = (const f4*)kern;
    const f4* __restrict__ bf = (const f4*)bias;

    f4 acc = (float)SHARDS * bf[d4];
#pragma unroll
    for (int sp = 0; sp < SHARDS; ++sp) {
        if (sp < s)
            acc += kf[(size_t)(sp * PER_IN + PER_IN - 1) * (D_MODEL / 4) + d4];
        else if (sp > s)
            acc += kf[(size_t)(sp * PER_IN) * (D_MODEL / 4) + d4];
    }
    // plain store: keep bsum resident in L2 for the gather kernel
    ((f4*)bsum)[(size_t)s * (D_MODEL / 4) + d4] = acc;
}

// Kernel 2: grid = SEQ*2 blocks; block handles one HALF (2048 dims) of one
// sequence position t, for BOTH batch rows.
// out[b,t,:] = kern[x[b,t]] + bsum[x[b,t]/PER_IN] + pos_flat[t,:]
__global__ __launch_bounds__(256)
void embed_gather_kernel(const int* __restrict__ x,
                         const float* __restrict__ kern,
                         const float* __restrict__ pos,   // flat [SEQ*D_MODEL]
                         const float* __restrict__ bsum,  // [SHARDS][D_MODEL]
                         float* __restrict__ out) {
    const int t    = blockIdx.x >> 1;
    const int half = blockIdx.x & 1;
    const int tid  = threadIdx.x;
    const int base = half * (D_MODEL / 8);   // f4 offset of this half-row (512 f4 per half)

    const int row0 = x[t];           // uniform, hot in L2
    const int row1 = x[SEQ + t];
    const int s0 = row0 / PER_IN;
    const int s1 = row1 / PER_IN;

    const f4* __restrict__ k0 = (const f4*)(kern + (size_t)row0 * D_MODEL) + base;
    const f4* __restrict__ k1 = (const f4*)(kern + (size_t)row1 * D_MODEL) + base;
    const f4* __restrict__ pr = (const f4*)(pos  + (size_t)t    * D_MODEL) + base;
    const f4* __restrict__ b0 = (const f4*)(bsum + (size_t)s0   * D_MODEL) + base;
    const f4* __restrict__ b1 = (const f4*)(bsum + (size_t)s1   * D_MODEL) + base;
    f4* __restrict__ o0 = (f4*)(out + (size_t)t         * D_MODEL) + base;
    f4* __restrict__ o1 = (f4*)(out + (size_t)(SEQ + t) * D_MODEL) + base;

    // 10 loads in flight, then combine + 4 nontemporal stores.
    // Streamed-once data (gathered rows, pos) uses nontemporal loads to
    // avoid L2 allocation; bsum (hot 128 KB) stays cached.
    f4 a0[2], a1[2], pv[2], v0[2], v1[2];
#pragma unroll
    for (int k = 0; k < 2; ++k) {
        const int i = tid + k * 256;
        a0[k] = __builtin_nontemporal_load(&k0[i]);
        a1[k] = __builtin_nontemporal_load(&k1[i]);
        pv[k] = __builtin_nontemporal_load(&pr[i]);
        v0[k] = b0[i];
        v1[k] = b1[i];
    }
#pragma unroll
    for (int k = 0; k < 2; ++k) {
        const int i = tid + k * 256;
        f4 r0 = a0[k] + v0[k] + pv[k];
        f4 r1 = a1[k] + v1[k] + pv[k];
        __builtin_nontemporal_store(r0, &o0[i]);
        __builtin_nontemporal_store(r1, &o1[i]);
    }
}

extern "C" void kernel_launch(void* const* d_in, const int* in_sizes, int n_in,
                              void* d_out, int out_size, void* d_ws, size_t ws_size,
                              hipStream_t stream) {
    const int*   x    = (const int*)  d_in[0];   // [BATCH, SEQ]
    const float* kern = (const float*)d_in[1];   // [N_VOCAB, D_MODEL]
    const float* bias = (const float*)d_in[2];   // [D_MODEL]
    const float* pos  = (const float*)d_in[3];   // [SHARDS, SEQ, PER_OUT] == flat [SEQ*D_MODEL]

    float* out  = (float*)d_out;                 // [BATCH, SEQ, D_MODEL]
    float* bsum = (float*)d_ws;                  // [SHARDS][D_MODEL] = 128 KB

    boundary_sums_kernel<<<SHARDS * (D_MODEL / 4 / 256), 256, 0, stream>>>(kern, bias, bsum);

    embed_gather_kernel<<<SEQ * 2, 256, 0, stream>>>(x, kern, pos, bsum, out);
}

// Round 6
// 36.046 us; speedup vs baseline: 1.0454x; 1.0454x over previous
//
#include <hip/hip_runtime.h>

#define N_VOCAB 50400
#define D_MODEL 4096
#define SHARDS  8
#define SEQ     2048
#define BATCH   2
#define PER_IN  6300   // N_VOCAB / SHARDS

typedef float f4 __attribute__((ext_vector_type(4)));

// Single fused kernel. Grid = SEQ*2 blocks; block handles one HALF (2048 dims)
// of sequence position t for BOTH batch rows.
//
// out[b,t,:] = kern[x[b,t]] + B[s_b] + 8*bias + pos_flat[t,:]
// where B[s] = sum_{sp<s} kern[sp*PER_IN+PER_IN-1] + sum_{sp>s} kern[sp*PER_IN]
// is computed on the fly from the 16 boundary rows (256 KB, L2-hot across all
// blocks), removing the serialized precompute kernel + graph node gap.
__global__ __launch_bounds__(256)
void fused_embed_kernel(const int* __restrict__ x,
                        const float* __restrict__ kern,
                        const float* __restrict__ bias,
                        const float* __restrict__ pos,   // flat [SEQ*D_MODEL]
                        float* __restrict__ out) {
    const int t    = blockIdx.x >> 1;
    const int half = blockIdx.x & 1;
    const int tid  = threadIdx.x;
    const int base = half * (D_MODEL / 8);   // f4 offset of this half-row

    const int row0 = x[t];           // wave-uniform
    const int row1 = x[SEQ + t];
    const int s0 = row0 / PER_IN;
    const int s1 = row1 / PER_IN;

    const f4* __restrict__ k0 = (const f4*)(kern + (size_t)row0 * D_MODEL) + base;
    const f4* __restrict__ k1 = (const f4*)(kern + (size_t)row1 * D_MODEL) + base;
    const f4* __restrict__ pr = (const f4*)(pos  + (size_t)t    * D_MODEL) + base;
    const f4* __restrict__ bi = (const f4*)bias + base;
    f4* __restrict__ o0 = (f4*)(out + (size_t)t         * D_MODEL) + base;
    f4* __restrict__ o1 = (f4*)(out + (size_t)(SEQ + t) * D_MODEL) + base;

    const int i0 = tid;
    const int i1 = tid + 256;

    // Streaming (HBM) loads first — longest latency, get them in flight.
    f4 a00 = k0[i0], a01 = k0[i1];
    f4 a10 = k1[i0], a11 = k1[i1];
    f4 p0  = pr[i0], p1  = pr[i1];
    f4 bv0 = bi[i0], bv1 = bi[i1];

    // Boundary-row accumulation (L2-hot: 16 distinct rows shared by all blocks).
    f4 acc00 = {0.f, 0.f, 0.f, 0.f}, acc01 = acc00;
    f4 acc10 = acc00, acc11 = acc00;
#pragma unroll
    for (int sp = 0; sp < SHARDS; ++sp) {
        if (sp != s0) {   // wave-uniform branch
            const size_t r = (size_t)(sp * PER_IN + (sp < s0 ? PER_IN - 1 : 0));
            const f4* __restrict__ p = (const f4*)(kern + r * D_MODEL) + base;
            acc00 += p[i0];
            acc01 += p[i1];
        }
        if (sp != s1) {
            const size_t r = (size_t)(sp * PER_IN + (sp < s1 ? PER_IN - 1 : 0));
            const f4* __restrict__ p = (const f4*)(kern + r * D_MODEL) + base;
            acc10 += p[i0];
            acc11 += p[i1];
        }
    }

    const float bs = (float)SHARDS;
    f4 r00 = a00 + acc00 + bs * bv0 + p0;
    f4 r01 = a01 + acc01 + bs * bv1 + p1;
    f4 r10 = a10 + acc10 + bs * bv0 + p0;
    f4 r11 = a11 + acc11 + bs * bv1 + p1;

    __builtin_nontemporal_store(r00, &o0[i0]);
    __builtin_nontemporal_store(r01, &o0[i1]);
    __builtin_nontemporal_store(r10, &o1[i0]);
    __builtin_nontemporal_store(r11, &o1[i1]);
}

extern "C" void kernel_launch(void* const* d_in, const int* in_sizes, int n_in,
                              void* d_out, int out_size, void* d_ws, size_t ws_size,
                              hipStream_t stream) {
    const int*   x    = (const int*)  d_in[0];   // [BATCH, SEQ]
    const float* kern = (const float*)d_in[1];   // [N_VOCAB, D_MODEL]
    const float* bias = (const float*)d_in[2];   // [D_MODEL]
    const float* pos  = (const float*)d_in[3];   // [SHARDS, SEQ, PER_OUT] == flat [SEQ*D_MODEL]

    float* out = (float*)d_out;                  // [BATCH, SEQ, D_MODEL]

    fused_embed_kernel<<<SEQ * 2, 256, 0, stream>>>(x, kern, bias, pos, out);
}

// Round 7
// 35.072 us; speedup vs baseline: 1.0744x; 1.0278x over previous
//
#include <hip/hip_runtime.h>

#define N_VOCAB 50400
#define D_MODEL 4096
#define SHARDS  8
#define SEQ     2048
#define BATCH   2
#define PER_IN  6300   // N_VOCAB / SHARDS

typedef float f4 __attribute__((ext_vector_type(4)));

// Kernel 1: bsum[s][d] = sum_{s'<s} kern[s'*PER_IN+PER_IN-1][d]
//                      + sum_{s'>s} kern[s'*PER_IN][d] + SHARDS*bias[d]
// grid = SHARDS * (D_MODEL/4/256) = 32 blocks.
__global__ __launch_bounds__(256)
void boundary_sums_kernel(const float* __restrict__ kern,
                          const float* __restrict__ bias,
                          float* __restrict__ bsum) {
    const int s  = blockIdx.x >> 2;                  // 0..7
    const int c  = blockIdx.x & 3;                   // 0..3
    const int d4 = c * 256 + threadIdx.x;            // f4 column index, 0..1023

    const f4* __restrict__ kf = (const f4*)kern;
    const f4* __restrict__ bf = (const f4*)bias;

    f4 acc = (float)SHARDS * bf[d4];
#pragma unroll
    for (int sp = 0; sp < SHARDS; ++sp) {
        if (sp < s)
            acc += kf[(size_t)(sp * PER_IN + PER_IN - 1) * (D_MODEL / 4) + d4];
        else if (sp > s)
            acc += kf[(size_t)(sp * PER_IN) * (D_MODEL / 4) + d4];
    }
    // plain store: keep bsum resident in L2 for the gather kernel
    ((f4*)bsum)[(size_t)s * (D_MODEL / 4) + d4] = acc;
}

// Kernel 2: grid = SEQ*2 blocks; block handles one HALF (2048 dims) of one
// sequence position t, for BOTH batch rows.
// out[b,t,:] = kern[x[b,t]] + bsum[x[b,t]/PER_IN] + pos_flat[t,:]
__global__ __launch_bounds__(256)
void embed_gather_kernel(const int* __restrict__ x,
                         const float* __restrict__ kern,
                         const float* __restrict__ pos,   // flat [SEQ*D_MODEL]
                         const float* __restrict__ bsum,  // [SHARDS][D_MODEL]
                         float* __restrict__ out) {
    const int t    = blockIdx.x >> 1;
    const int half = blockIdx.x & 1;
    const int tid  = threadIdx.x;
    const int base = half * (D_MODEL / 8);   // f4 offset of this half-row (512 f4 per half)

    const int row0 = x[t];           // uniform -> scalar load
    const int row1 = x[SEQ + t];
    const int s0 = row0 / PER_IN;
    const int s1 = row1 / PER_IN;

    const f4* __restrict__ k0 = (const f4*)(kern + (size_t)row0 * D_MODEL) + base;
    const f4* __restrict__ k1 = (const f4*)(kern + (size_t)row1 * D_MODEL) + base;
    const f4* __restrict__ pr = (const f4*)(pos  + (size_t)t    * D_MODEL) + base;
    const f4* __restrict__ b0 = (const f4*)(bsum + (size_t)s0   * D_MODEL) + base;
    const f4* __restrict__ b1 = (const f4*)(bsum + (size_t)s1   * D_MODEL) + base;
    f4* __restrict__ o0 = (f4*)(out + (size_t)t         * D_MODEL) + base;
    f4* __restrict__ o1 = (f4*)(out + (size_t)(SEQ + t) * D_MODEL) + base;

    // 10 loads in flight, then combine + 4 plain stores (A/B vs R4's nt stores).
    f4 a0[2], a1[2], pv[2], v0[2], v1[2];
#pragma unroll
    for (int k = 0; k < 2; ++k) {
        const int i = tid + k * 256;
        a0[k] = k0[i];
        a1[k] = k1[i];
        pv[k] = pr[i];
        v0[k] = b0[i];
        v1[k] = b1[i];
    }
#pragma unroll
    for (int k = 0; k < 2; ++k) {
        const int i = tid + k * 256;
        o0[i] = a0[k] + v0[k] + pv[k];
        o1[i] = a1[k] + v1[k] + pv[k];
    }
}

extern "C" void kernel_launch(void* const* d_in, const int* in_sizes, int n_in,
                              void* d_out, int out_size, void* d_ws, size_t ws_size,
                              hipStream_t stream) {
    const int*   x    = (const int*)  d_in[0];   // [BATCH, SEQ]
    const float* kern = (const float*)d_in[1];   // [N_VOCAB, D_MODEL]
    const float* bias = (const float*)d_in[2];   // [D_MODEL]
    const float* pos  = (const float*)d_in[3];   // [SHARDS, SEQ, PER_OUT] == flat [SEQ*D_MODEL]

    float* out  = (float*)d_out;                 // [BATCH, SEQ, D_MODEL]
    float* bsum = (float*)d_ws;                  // [SHARDS][D_MODEL] = 128 KB

    boundary_sums_kernel<<<SHARDS * (D_MODEL / 4 / 256), 256, 0, stream>>>(kern, bias, bsum);

    embed_gather_kernel<<<SEQ * 2, 256, 0, stream>>>(x, kern, pos, bsum, out);
}

// Round 8
// 34.272 us; speedup vs baseline: 1.0995x; 1.0234x over previous
//
#include <hip/hip_runtime.h>

#define N_VOCAB 50400
#define D_MODEL 4096
#define SHARDS  8
#define SEQ     2048
#define BATCH   2
#define PER_IN  6300   // N_VOCAB / SHARDS

typedef float f4 __attribute__((ext_vector_type(4)));

// Kernel 1: bsum[s][d] = sum_{s'<s} kern[s'*PER_IN+PER_IN-1][d]
//                      + sum_{s'>s} kern[s'*PER_IN][d] + SHARDS*bias[d]
// grid = SHARDS * (D_MODEL/4/256) = 32 blocks.
__global__ __launch_bounds__(256)
void boundary_sums_kernel(const float* __restrict__ kern,
                          const float* __restrict__ bias,
                          float* __restrict__ bsum) {
    const int s  = blockIdx.x >> 2;                  // 0..7
    const int c  = blockIdx.x & 3;                   // 0..3
    const int d4 = c * 256 + threadIdx.x;            // f4 column index, 0..1023

    const f4* __restrict__ kf = (const f4*)kern;
    const f4* __restrict__ bf = (const f4*)bias;

    f4 acc = (float)SHARDS * bf[d4];
#pragma unroll
    for (int sp = 0; sp < SHARDS; ++sp) {
        if (sp < s)
            acc += kf[(size_t)(sp * PER_IN + PER_IN - 1) * (D_MODEL / 4) + d4];
        else if (sp > s)
            acc += kf[(size_t)(sp * PER_IN) * (D_MODEL / 4) + d4];
    }
    ((f4*)bsum)[(size_t)s * (D_MODEL / 4) + d4] = acc;
}

// Kernel 2: grid = SEQ*2 blocks; block handles one HALF (2048 dims) of one
// sequence position t, for BOTH batch rows.
// out[b,t,:] = kern[x[b,t]] + bsum[x[b,t]/PER_IN] + pos_flat[t,:]
// x-independent pos loads are issued BEFORE the x-dependent address chain so
// the block's memory pipe starts immediately.
__global__ __launch_bounds__(256)
void embed_gather_kernel(const int* __restrict__ x,
                         const float* __restrict__ kern,
                         const float* __restrict__ pos,   // flat [SEQ*D_MODEL]
                         const float* __restrict__ bsum,  // [SHARDS][D_MODEL]
                         float* __restrict__ out) {
    const int t    = blockIdx.x >> 1;
    const int half = blockIdx.x & 1;
    const int tid  = threadIdx.x;
    const int base = half * (D_MODEL / 8);   // f4 offset of this half-row (512 f4 per half)

    const int i0 = tid;
    const int i1 = tid + 256;

    // Phase 0: x-independent loads in flight first.
    const f4* __restrict__ pr = (const f4*)(pos + (size_t)t * D_MODEL) + base;
    f4 p0 = pr[i0];
    f4 p1 = pr[i1];

    // Phase 1: scalar index loads + dependent streams.
    const int row0 = x[t];           // uniform -> s_load
    const int row1 = x[SEQ + t];
    const int s0 = row0 / PER_IN;
    const int s1 = row1 / PER_IN;

    const f4* __restrict__ k0 = (const f4*)(kern + (size_t)row0 * D_MODEL) + base;
    const f4* __restrict__ k1 = (const f4*)(kern + (size_t)row1 * D_MODEL) + base;
    const f4* __restrict__ b0 = (const f4*)(bsum + (size_t)s0   * D_MODEL) + base;
    const f4* __restrict__ b1 = (const f4*)(bsum + (size_t)s1   * D_MODEL) + base;
    f4* __restrict__ o0 = (f4*)(out + (size_t)t         * D_MODEL) + base;
    f4* __restrict__ o1 = (f4*)(out + (size_t)(SEQ + t) * D_MODEL) + base;

    f4 a00 = k0[i0], a01 = k0[i1];
    f4 a10 = k1[i0], a11 = k1[i1];
    f4 v00 = b0[i0], v01 = b0[i1];
    f4 v10 = b1[i0], v11 = b1[i1];

    f4 r00 = a00 + v00 + p0;
    f4 r01 = a01 + v01 + p1;
    f4 r10 = a10 + v10 + p0;
    f4 r11 = a11 + v11 + p1;

    __builtin_nontemporal_store(r00, &o0[i0]);
    __builtin_nontemporal_store(r01, &o0[i1]);
    __builtin_nontemporal_store(r10, &o1[i0]);
    __builtin_nontemporal_store(r11, &o1[i1]);
}

extern "C" void kernel_launch(void* const* d_in, const int* in_sizes, int n_in,
                              void* d_out, int out_size, void* d_ws, size_t ws_size,
                              hipStream_t stream) {
    const int*   x    = (const int*)  d_in[0];   // [BATCH, SEQ]
    const float* kern = (const float*)d_in[1];   // [N_VOCAB, D_MODEL]
    const float* bias = (const float*)d_in[2];   // [D_MODEL]
    const float* pos  = (const float*)d_in[3];   // [SHARDS, SEQ, PER_OUT] == flat [SEQ*D_MODEL]

    float* out  = (float*)d_out;                 // [BATCH, SEQ, D_MODEL]
    float* bsum = (float*)d_ws;                  // [SHARDS][D_MODEL] = 128 KB

    boundary_sums_kernel<<<SHARDS * (D_MODEL / 4 / 256), 256, 0, stream>>>(kern, bias, bsum);

    embed_gather_kernel<<<SEQ * 2, 256, 0, stream>>>(x, kern, pos, bsum, out);
}